// Round 5
// 209.792 us; speedup vs baseline: 1.0262x; 1.0262x over previous
//
#include <hip/hip_runtime.h>

// B=4,H=16,S=2048,D=64 fp32 attention, bf16-MFMA flash kernel, round 11
// (= round 10 resubmitted verbatim. Still never executed: r7/r8/r10
//  GPUAcquisitionTimeout, r9 container-provisioning failure -- all
//  pre-execution infra. No evidence to update on; not stacking
//  unmeasured changes.)
// Counters r6: MfmaUtil 23 / VALUBusy 26 / HBM 42% / occ 36% -> nothing
// saturated => serialization-bound. Three changes vs r6:
//  1. T12 in-register P: v_cvt_pk_bf16_f32 + v_permlane32_swap_b32 build the
//     PV B-fragments directly from the QK^T accumulator. Removes the per-wave
//     Ps LDS round-trip (8 ds_write_b64 + 4 ds_read_b128 + lgkmcnt(0) per
//     tile). Fragments are built & consumed immediately, static indexing
//     only (no runtime-indexed arrays -> no scratch spill, unlike round 5).
//  2. Double-buffered Ks/Vt in the LDS freed by Ps (same 36 KB footprint):
//     ONE __syncthreads per K-tile instead of two.
//  3. XCD-aware blockIdx swizzle (bijective, 1024%8==0): all 16 q-blocks of a
//     (b,h) land on one XCD so K/V re-reads hit that XCD's L2
//     (FETCH was 357 MB vs ~100 MB compulsory).
// Layouts (m74/m101-verified): A/B frag [i=lane&31][k=(lane>>5)*8+j],
// C/D: col=lane&31, row=(reg&3)+8*(reg>>2)+4*(lane>>5).
// permlane32_swap recipe (m214v22-verified): for frag base b,
//   A = swap(pk2(p[b],p[b+1]), pk2(p[b+4],p[b+5]))
//   B = swap(pk2(p[b+2],p[b+3]), pk2(p[b+6],p[b+7]))
//   frag words = {A[0], B[0], A[1], B[1]}  (each swap fills two words).

#define S_LEN 2048
#define D_LEN 64
#define QT    128
#define TK    64
#define THREADS 256
#define KSTR  72   // halfwords per LDS row (144 B): 16B-aligned rows, 4-way max
#define NT    (S_LEN / TK)

typedef __attribute__((ext_vector_type(8)))  short bf16x8;
typedef __attribute__((ext_vector_type(16))) float f32x16;

#if __has_builtin(__builtin_amdgcn_exp2f)
#define FAST_EXP2(x) __builtin_amdgcn_exp2f(x)
#else
#define FAST_EXP2(x) __expf((x) * 0.69314718055994531f)
#endif

// HW packed f32->bf16: D[15:0]=bf16(a), D[31:16]=bf16(b). One VALU op.
__device__ __forceinline__ unsigned pk2(float a, float b) {
    unsigned r;
    asm("v_cvt_pk_bf16_f32 %0, %1, %2" : "=v"(r) : "v"(a), "v"(b));
    return r;
}

// v_permlane32_swap_b32 a, b: swaps a's upper-32-lane half with b's
// lower-32-lane half; both outputs are usable fragment words.
__device__ __forceinline__ void pl32(unsigned& a, unsigned& b) {
    asm("v_permlane32_swap_b32 %0, %1" : "+v"(a), "+v"(b));
}

__global__ __launch_bounds__(THREADS, 4)
void attn_mfma32(const float* __restrict__ qg,
                 const float* __restrict__ kg,
                 const float* __restrict__ vg,
                 float* __restrict__ og)
{
    __shared__ alignas(16) unsigned short Ks[2][TK * KSTR];      // [key][d]
    __shared__ alignas(16) unsigned short Vt[2][D_LEN * KSTR];   // [d][key]

    const int tid  = threadIdx.x;
    const int w    = tid >> 6;
    const int lane = tid & 63;
    const int q31  = lane & 31;
    const int hi   = lane >> 5;

    // XCD swizzle: blocks round-robin over 8 XCDs; remap so XCD x gets a
    // contiguous chunk -> all 16 q-blocks of one bh share one XCD's L2.
    const int swz   = (blockIdx.x & 7) * 128 + (blockIdx.x >> 3);
    const int bh    = swz >> 4;
    const int qblk  = swz & 15;
    const int qrow0 = qblk * QT + w * 32;

    const float* kbase = kg + (size_t)bh * S_LEN * D_LEN;
    const float* vbase = vg + (size_t)bh * S_LEN * D_LEN;

    // ---- Q fragments: B-operand, lane holds Q[qrow0+q31][kf*16+hi*8+j] ----
    const float c = 0.125f * 1.4426950408889634f;
    bf16x8 qf[4];
    {
        const float* qp = qg + ((size_t)bh * S_LEN + qrow0 + q31) * D_LEN + hi * 8;
#pragma unroll
        for (int kf = 0; kf < 4; ++kf) {
            float4 a = ((const float4*)(qp + kf * 16))[0];
            float4 b = ((const float4*)(qp + kf * 16))[1];
            uint4 u = make_uint4(pk2(a.x * c, a.y * c), pk2(a.z * c, a.w * c),
                                 pk2(b.x * c, b.y * c), pk2(b.z * c, b.w * c));
            qf[kf] = __builtin_bit_cast(bf16x8, u);
        }
    }

    f32x16 o0, o1;
#pragma unroll
    for (int i = 0; i < 16; ++i) { o0[i] = 0.f; o1[i] = 0.f; }
    float lsum = 0.f;

    // ---- staging assignment ----
    // K: thread -> key=tid>>2 (0..63), 16-d chunk c=tid&3; 4 float4 coalesced.
    const int skey = tid >> 2;
    const int sc   = tid & 3;
    const float4* kptr = (const float4*)kbase + (size_t)skey * 16 + sc * 4;
    // V: lane = d, wave w covers keys w*16..w*16+15; scalar coalesced loads.
    const float* vptr = vbase + (size_t)(w * 16) * D_LEN + lane;

    float4 kreg[4];
    float  vreg[16];
#pragma unroll
    for (int i = 0; i < 4; ++i) kreg[i] = kptr[i];
#pragma unroll
    for (int r = 0; r < 16; ++r) vreg[r] = vptr[r * 64];

    auto stage = [&](int buf) {
        uint4 u0 = make_uint4(pk2(kreg[0].x, kreg[0].y), pk2(kreg[0].z, kreg[0].w),
                              pk2(kreg[1].x, kreg[1].y), pk2(kreg[1].z, kreg[1].w));
        uint4 u1 = make_uint4(pk2(kreg[2].x, kreg[2].y), pk2(kreg[2].z, kreg[2].w),
                              pk2(kreg[3].x, kreg[3].y), pk2(kreg[3].z, kreg[3].w));
        *(uint4*)&Ks[buf][skey * KSTR + sc * 16]     = u0;
        *(uint4*)&Ks[buf][skey * KSTR + sc * 16 + 8] = u1;
        uint4 v0 = make_uint4(pk2(vreg[0], vreg[1]),   pk2(vreg[2], vreg[3]),
                              pk2(vreg[4], vreg[5]),   pk2(vreg[6], vreg[7]));
        uint4 v1 = make_uint4(pk2(vreg[8], vreg[9]),   pk2(vreg[10], vreg[11]),
                              pk2(vreg[12], vreg[13]), pk2(vreg[14], vreg[15]));
        *(uint4*)&Vt[buf][lane * KSTR + w * 16]     = v0;
        *(uint4*)&Vt[buf][lane * KSTR + w * 16 + 8] = v1;
    };

    stage(0);
    __syncthreads();

    for (int t = 0; t < NT; ++t) {
        const int cur = t & 1;

        // ---- prefetch next tile into regs (latency hidden under compute) ----
        if (t + 1 < NT) {
            const float4* kn = kptr + (size_t)(t + 1) * (TK * 16);
#pragma unroll
            for (int i = 0; i < 4; ++i) kreg[i] = kn[i];
            const float* vn = vptr + (size_t)(t + 1) * (TK * D_LEN);
#pragma unroll
            for (int r = 0; r < 16; ++r) vreg[r] = vn[r * 64];
        }

        // ---- fused: S^T = K.Q^T, exp2, in-register P -> O^T += V^T.P^T ----
#pragma unroll
        for (int kt = 0; kt < 2; ++kt) {
            f32x16 s;
#pragma unroll
            for (int i = 0; i < 16; ++i) s[i] = 0.f;
#pragma unroll
            for (int kf = 0; kf < 4; ++kf) {
                bf16x8 ka = *(const bf16x8*)&Ks[cur][(kt * 32 + q31) * KSTR + kf * 16 + hi * 8];
                s = __builtin_amdgcn_mfma_f32_32x32x16_bf16(ka, qf[kf], s, 0, 0, 0);
            }
            // lane holds keys kt*32 + g*8 + hi*4 + (0..3) as s[4g+d], q = q31
#pragma unroll
            for (int f = 0; f < 2; ++f) {
                const int b = f * 8;
                float p0 = FAST_EXP2(s[b + 0]), p1 = FAST_EXP2(s[b + 1]);
                float p2 = FAST_EXP2(s[b + 2]), p3 = FAST_EXP2(s[b + 3]);
                float p4 = FAST_EXP2(s[b + 4]), p5 = FAST_EXP2(s[b + 5]);
                float p6 = FAST_EXP2(s[b + 6]), p7 = FAST_EXP2(s[b + 7]);
                lsum += ((p0 + p1) + (p2 + p3)) + ((p4 + p5) + (p6 + p7));
                unsigned a0 = pk2(p0, p1), a1 = pk2(p4, p5);
                unsigned b0 = pk2(p2, p3), b1 = pk2(p6, p7);
                pl32(a0, a1);
                pl32(b0, b1);
                uint4 u = make_uint4(a0, b0, a1, b1);
                bf16x8 pb = __builtin_bit_cast(bf16x8, u);
                const int kq = kt * 2 + f;
                bf16x8 va0 = *(const bf16x8*)&Vt[cur][q31 * KSTR + kq * 16 + hi * 8];
                bf16x8 va1 = *(const bf16x8*)&Vt[cur][(32 + q31) * KSTR + kq * 16 + hi * 8];
                o0 = __builtin_amdgcn_mfma_f32_32x32x16_bf16(va0, pb, o0, 0, 0, 0);
                o1 = __builtin_amdgcn_mfma_f32_32x32x16_bf16(va1, pb, o1, 0, 0, 0);
            }
        }

        // ---- stage next tile into the other buffer; single barrier ----
        if (t + 1 < NT) {
            stage(cur ^ 1);
            __syncthreads();
        }
    }

    // ---- epilogue ----
    float l = lsum + __shfl_xor(lsum, 32);
    const float inv = 1.0f / l;
    float* ob = og + ((size_t)bh * S_LEN + qrow0 + q31) * D_LEN;
#pragma unroll
    for (int g = 0; g < 4; ++g) {
        float4 f0 = make_float4(o0[4 * g + 0] * inv, o0[4 * g + 1] * inv,
                                o0[4 * g + 2] * inv, o0[4 * g + 3] * inv);
        ((float4*)(ob + g * 8 + hi * 4))[0] = f0;              // d = 8g + 4hi
        float4 f1 = make_float4(o1[4 * g + 0] * inv, o1[4 * g + 1] * inv,
                                o1[4 * g + 2] * inv, o1[4 * g + 3] * inv);
        ((float4*)(ob + 32 + g * 8 + hi * 4))[0] = f1;         // d = 32 + 8g + 4hi
    }
}

extern "C" void kernel_launch(void* const* d_in, const int* in_sizes, int n_in,
                              void* d_out, int out_size, void* d_ws, size_t ws_size,
                              hipStream_t stream)
{
    const float* q = (const float*)d_in[0];
    const float* k = (const float*)d_in[1];
    const float* v = (const float*)d_in[2];
    float* out = (float*)d_out;

    dim3 grid(64 * (S_LEN / QT));   // 1024 blocks = 4/CU resident
    dim3 block(THREADS);
    attn_mfma32<<<grid, block, 0, stream>>>(q, k, v, out);
}